// Round 1
// baseline (15062.556 us; speedup 1.0000x reference)
//
#include <hip/hip_runtime.h>

// ---------------------------------------------------------------------------
// TRecTransformer: 4-layer encoder/decoder with linear attention, MI355X.
// Round 0: correctness-first. fp32 activations in ws, dtype-adaptive input
// loads (bf16 vs fp32 auto-detected from enc_ln's first word).
// ---------------------------------------------------------------------------

#define NB 4
#define NSEQ 4096
#define NH 8
#define DQ 64
#define DM 512
#define DFF 2048
#define MROWS (NB * NSEQ)          // 16384
#define SZ ((long)MROWS * DM)      // 8388608 floats = 32 MB per buffer

typedef unsigned short u16;
struct US4 { u16 x, y, z, w; };

__device__ __forceinline__ float bf2f(u16 u) {
  union { unsigned u; float f; } v; v.u = ((unsigned)u) << 16; return v.f;
}
__device__ __forceinline__ u16 f2bf(float f) {
  union { float f; unsigned u; } v; v.f = f;
  unsigned r = v.u + 0x7FFFu + ((v.u >> 16) & 1u);
  return (u16)(r >> 16);
}
__device__ __forceinline__ float ldin(const void* p, long i, int bf) {
  return bf ? bf2f(((const u16*)p)[i]) : ((const float*)p)[i];
}

// --- dtype probe: enc_ln starts with scale=1.0s. fp32 word0=0x3F800000,
//     bf16 word0 = (1.0bf16,1.0bf16) = 0x3F803F80.
__global__ void detect_k(const unsigned* __restrict__ lnp, int* __restrict__ flag) {
  if (threadIdx.x == 0 && blockIdx.x == 0)
    *flag = (lnp[0] == 0x3F803F80u) ? 1 : 0;
}

// --- embed: H[b,n,:] = concat(x[b,n,0:2], pe[n,0:510]) ---------------------
__global__ __launch_bounds__(256) void embed_k(
    const void* __restrict__ xin, const void* __restrict__ pe,
    float* __restrict__ H, const int* __restrict__ flag) {
  int bf = *flag;
  long idx = (long)blockIdx.x * 256 + threadIdx.x;   // < MROWS*DM
  long row = idx >> 9;
  int  c   = (int)(idx & 511);
  long n   = row & (NSEQ - 1);
  H[idx] = (c < 2) ? ldin(xin, row * 2 + c, bf)
                   : ldin(pe, n * 510 + (c - 2), bf);
}

// --- GEMM: C[M,512] = act(A[M,512] @ W[512col-slice] + bias), opt accumulate
// A fp32 ws row-major lda=512 (K is always 512 in this network).
// W dtype-adaptive, element offset woff, leading dim ldw.
// act: 0 none, 1 elu(x)+1, 2 relu.
__global__ __launch_bounds__(256) void gemm_k(
    const float* __restrict__ A,
    const void* __restrict__ W, long woff, int ldw,
    const void* __restrict__ bias, long boff, int hasb,
    float* __restrict__ C, int act, int accum,
    const int* __restrict__ flag) {
  int bf = *flag;
  __shared__ float Ast[16][68];   // transposed A tile, padded stride
  __shared__ float Ws[16][64];
  int tid = threadIdx.x;
  int tx = tid & 15, ty = tid >> 4;
  long row0 = (long)blockIdx.y * 64;
  int  col0 = blockIdx.x * 64;
  int ar = tid >> 2;              // 0..63
  int ac = (tid & 3) << 2;        // 0,4,8,12
  int wr = tid >> 4;              // 0..15
  int wc = (tid & 15) << 2;       // 0..60
  const float* Ap = A + (row0 + ar) * DM + ac;
  float acc[4][4] = {};
  for (int k0 = 0; k0 < DM; k0 += 16) {
    float4 av = *(const float4*)(Ap + k0);
    float w0, w1, w2, w3;
    long widx = woff + (long)(k0 + wr) * ldw + col0 + wc;
    if (bf) {
      US4 u = *(const US4*)((const u16*)W + widx);
      w0 = bf2f(u.x); w1 = bf2f(u.y); w2 = bf2f(u.z); w3 = bf2f(u.w);
    } else {
      float4 fv = *(const float4*)((const float*)W + widx);
      w0 = fv.x; w1 = fv.y; w2 = fv.z; w3 = fv.w;
    }
    __syncthreads();
    Ast[ac + 0][ar] = av.x; Ast[ac + 1][ar] = av.y;
    Ast[ac + 2][ar] = av.z; Ast[ac + 3][ar] = av.w;
    Ws[wr][wc + 0] = w0; Ws[wr][wc + 1] = w1;
    Ws[wr][wc + 2] = w2; Ws[wr][wc + 3] = w3;
    __syncthreads();
#pragma unroll
    for (int kk = 0; kk < 16; kk++) {
      float4 a4 = *(const float4*)&Ast[kk][ty << 2];
      float4 b4 = *(const float4*)&Ws[kk][tx << 2];
      float a[4] = {a4.x, a4.y, a4.z, a4.w};
      float b[4] = {b4.x, b4.y, b4.z, b4.w};
#pragma unroll
      for (int i = 0; i < 4; i++)
#pragma unroll
        for (int j = 0; j < 4; j++) acc[i][j] += a[i] * b[j];
    }
  }
  float bv[4] = {0.f, 0.f, 0.f, 0.f};
  if (hasb) {
#pragma unroll
    for (int j = 0; j < 4; j++) bv[j] = ldin(bias, boff + col0 + (tx << 2) + j, bf);
  }
#pragma unroll
  for (int i = 0; i < 4; i++) {
    long ro = (row0 + (ty << 2) + i) * DM + col0 + (tx << 2);
    float4 cv;
    float t0 = acc[i][0] + bv[0], t1 = acc[i][1] + bv[1];
    float t2 = acc[i][2] + bv[2], t3 = acc[i][3] + bv[3];
    if (act == 1) {
      t0 = (t0 > 0.f) ? t0 + 1.f : expf(t0);
      t1 = (t1 > 0.f) ? t1 + 1.f : expf(t1);
      t2 = (t2 > 0.f) ? t2 + 1.f : expf(t2);
      t3 = (t3 > 0.f) ? t3 + 1.f : expf(t3);
    } else if (act == 2) {
      t0 = fmaxf(t0, 0.f); t1 = fmaxf(t1, 0.f);
      t2 = fmaxf(t2, 0.f); t3 = fmaxf(t3, 0.f);
    }
    cv.x = t0; cv.y = t1; cv.z = t2; cv.w = t3;
    float4* Cp = (float4*)&C[ro];
    if (accum) {
      float4 old = *Cp;
      cv.x += old.x; cv.y += old.y; cv.z += old.z; cv.w += old.w;
    }
    *Cp = cv;
  }
}

// --- kv partial: per (b,h,chunk): kv_part[64][64] += k_n ⊗ v_n over 512 rows
__global__ __launch_bounds__(256) void kv_partial_k(
    const float* __restrict__ Kb, const float* __restrict__ Vb,
    float* __restrict__ kvp, float* __restrict__ ksp) {
  int bh = blockIdx.x;           // 0..31
  int b = bh >> 3, h = bh & 7;
  int nc = blockIdx.y;           // 0..7
  int tid = threadIdx.x;
  __shared__ float Ks[8][64], Vs[8][64];
  float acc[16] = {};
  float ks = 0.f;
  int d  = tid >> 2;             // 0..63
  int e0 = (tid & 3) << 4;       // 0,16,32,48
  int lr = tid >> 5;             // 0..7
  int lc = (tid & 31) << 1;      // 0..62
  long base = ((long)b * NSEQ + (long)nc * 512) * DM + h * DQ;
  for (int n8 = 0; n8 < 64; n8++) {
    long g = base + (long)(n8 * 8 + lr) * DM + lc;
    float2 kk2 = *(const float2*)(Kb + g);
    float2 vv2 = *(const float2*)(Vb + g);
    __syncthreads();
    Ks[lr][lc] = kk2.x; Ks[lr][lc + 1] = kk2.y;
    Vs[lr][lc] = vv2.x; Vs[lr][lc + 1] = vv2.y;
    __syncthreads();
#pragma unroll
    for (int r2 = 0; r2 < 8; r2++) {
      float kd = Ks[r2][d];
#pragma unroll
      for (int m = 0; m < 16; m++) acc[m] += kd * Vs[r2][e0 + m];
    }
    if (tid < 64) {
#pragma unroll
      for (int r2 = 0; r2 < 8; r2++) ks += Ks[r2][tid];
    }
  }
  long ob = ((long)bh * 8 + nc) * 4096 + (long)d * 64 + e0;
#pragma unroll
  for (int m = 0; m < 16; m++) kvp[ob + m] = acc[m];
  if (tid < 64) ksp[((long)bh * 8 + nc) * 64 + tid] = ks;
}

// --- kv reduce: sum the 8 chunks ------------------------------------------
__global__ __launch_bounds__(256) void kv_reduce_k(
    const float* __restrict__ kvp, const float* __restrict__ ksp,
    float* __restrict__ kv, float* __restrict__ ksum) {
  int bh = blockIdx.x;
  int tid = threadIdx.x;
  for (int i = tid; i < 4096; i += 256) {
    float s = 0.f;
#pragma unroll
    for (int c = 0; c < 8; c++) s += kvp[((long)bh * 8 + c) * 4096 + i];
    kv[(long)bh * 4096 + i] = s;
  }
  if (tid < 64) {
    float s = 0.f;
#pragma unroll
    for (int c = 0; c < 8; c++) s += ksp[((long)bh * 8 + c) * 64 + tid];
    ksum[(long)bh * 64 + tid] = s;
  }
}

// --- o = (q @ kv) / (q·ksum + eps), per (b,h), 64 rows per block ----------
__global__ __launch_bounds__(256) void attn_o_k(
    const float* __restrict__ Qb, const float* __restrict__ kv,
    const float* __restrict__ ksum, float* __restrict__ Ob) {
  int bh = blockIdx.x;
  int b = bh >> 3, h = bh & 7;
  int n0 = blockIdx.y * 64;
  int tid = threadIdx.x;
  __shared__ float Qs[64][65];
  __shared__ float KVs[64][64];
  __shared__ float ks_s[64];
  __shared__ float dinv[64];
  for (int i = tid; i < 4096; i += 256) {
    KVs[i >> 6][i & 63] = kv[(long)bh * 4096 + i];
    Qs[i >> 6][i & 63] =
        Qb[((long)b * NSEQ + n0 + (i >> 6)) * DM + h * DQ + (i & 63)];
  }
  if (tid < 64) ks_s[tid] = ksum[(long)bh * 64 + tid];
  __syncthreads();
  if (tid < 64) {
    float s = 0.f;
#pragma unroll
    for (int dd = 0; dd < 64; dd++) s += Qs[tid][dd] * ks_s[dd];
    dinv[tid] = 1.f / (s + 1e-6f);
  }
  __syncthreads();
  int tx = tid & 15, ty = tid >> 4;
  float acc[4][4] = {};
#pragma unroll 4
  for (int dd = 0; dd < 64; dd++) {
    float a[4];
#pragma unroll
    for (int i = 0; i < 4; i++) a[i] = Qs[(ty << 2) + i][dd];
    float4 b4 = *(const float4*)&KVs[dd][tx << 2];
    float b[4] = {b4.x, b4.y, b4.z, b4.w};
#pragma unroll
    for (int i = 0; i < 4; i++)
#pragma unroll
      for (int j = 0; j < 4; j++) acc[i][j] += a[i] * b[j];
  }
#pragma unroll
  for (int i = 0; i < 4; i++) {
    float z = dinv[(ty << 2) + i];
    long ro = ((long)b * NSEQ + n0 + (ty << 2) + i) * DM + h * DQ + (tx << 2);
#pragma unroll
    for (int j = 0; j < 4; j++) Ob[ro + j] = acc[i][j] * z;
  }
}

// --- Out = LN(X (+Y)) * scale + bias --------------------------------------
__global__ __launch_bounds__(256) void add_ln_k(
    const float* __restrict__ X, const float* __restrict__ Y,
    const void* __restrict__ lnp, long lnoff, float* __restrict__ Out,
    const int* __restrict__ flag) {
  int bf = *flag;
  long r = blockIdx.x;
  int tid = threadIdx.x;
  long base = r * DM;
  float x0 = X[base + tid], x1 = X[base + tid + 256];
  if (Y) { x0 += Y[base + tid]; x1 += Y[base + tid + 256]; }
  float s = x0 + x1, sq = x0 * x0 + x1 * x1;
  for (int off = 32; off; off >>= 1) {
    s  += __shfl_down(s, off, 64);
    sq += __shfl_down(sq, off, 64);
  }
  __shared__ float red[8];
  __shared__ float mv[2];
  int w = tid >> 6;
  if ((tid & 63) == 0) { red[w] = s; red[4 + w] = sq; }
  __syncthreads();
  if (tid == 0) {
    float S = red[0] + red[1] + red[2] + red[3];
    float Q2 = red[4] + red[5] + red[6] + red[7];
    float m = S * (1.f / 512.f);
    float v = Q2 * (1.f / 512.f) - m * m;
    mv[0] = m; mv[1] = rsqrtf(v + 1e-5f);
  }
  __syncthreads();
  float m = mv[0], rs = mv[1];
  Out[base + tid] =
      (x0 - m) * rs * ldin(lnp, lnoff + tid, bf) + ldin(lnp, lnoff + 512 + tid, bf);
  Out[base + tid + 256] =
      (x1 - m) * rs * ldin(lnp, lnoff + 256 + tid, bf) + ldin(lnp, lnoff + 768 + tid, bf);
}

// --- heads: out[r,0]=t·ampW+ab, out[r,1]=tanh(t·phW+pb) --------------------
__global__ __launch_bounds__(256) void heads_k(
    const float* __restrict__ Tb, const void* __restrict__ aW,
    const void* __restrict__ pW, const void* __restrict__ ab,
    const void* __restrict__ pb, void* __restrict__ out,
    const int* __restrict__ flag) {
  int bf = *flag;
  int tid = threadIdx.x, w = tid >> 6, ln = tid & 63;
  long r = (long)blockIdx.x * 4 + w;
  float sa = 0.f, sp = 0.f;
#pragma unroll
  for (int i = 0; i < 8; i++) {
    int d = ln + i * 64;
    float xv = Tb[r * DM + d];
    sa += xv * ldin(aW, d, bf);
    sp += xv * ldin(pW, d, bf);
  }
  for (int off = 32; off; off >>= 1) {
    sa += __shfl_down(sa, off, 64);
    sp += __shfl_down(sp, off, 64);
  }
  if (ln == 0) {
    float amp = sa + ldin(ab, 0, bf);
    float ph  = tanhf(sp + ldin(pb, 0, bf));
    if (bf) {
      ((u16*)out)[r * 2]     = f2bf(amp);
      ((u16*)out)[r * 2 + 1] = f2bf(ph);
    } else {
      ((float*)out)[r * 2]     = amp;
      ((float*)out)[r * 2 + 1] = ph;
    }
  }
}

// ---------------------------------------------------------------------------
extern "C" void kernel_launch(void* const* d_in, const int* in_sizes, int n_in,
                              void* d_out, int out_size, void* d_ws, size_t ws_size,
                              hipStream_t stream) {
  const void* x       = d_in[0];
  const void* tfc     = d_in[1];
  const void* pe_s    = d_in[2];
  const void* pe_t    = d_in[3];
  const void* enc_W   = d_in[4];
  const void* enc_b   = d_in[5];
  const void* enc_ln  = d_in[6];
  const void* enc_fW1 = d_in[7];
  const void* enc_fb1 = d_in[8];
  const void* enc_fW2 = d_in[9];
  const void* enc_fb2 = d_in[10];
  const void* enc_fln = d_in[11];
  const void* dec_W   = d_in[12];
  const void* dec_b   = d_in[13];
  const void* dec_ln  = d_in[14];
  const void* dec_fW1 = d_in[15];
  const void* dec_fb1 = d_in[16];
  const void* dec_fW2 = d_in[17];
  const void* dec_fb2 = d_in[18];
  const void* dec_fln = d_in[19];
  const void* amp_W   = d_in[20];
  const void* amp_b   = d_in[21];
  const void* ph_W    = d_in[22];
  const void* ph_b    = d_in[23];

  // ws layout (fp32): needs ~202 MB.
  float* f   = (float*)d_ws;
  float* H   = f;               // residual stream (enc h / dec t)
  float* MEM = f + 1 * SZ;      // encoder memory
  float* Q   = f + 2 * SZ;      // q buffer; reused as FFN hidden chunk
  float* Kb  = f + 3 * SZ;      // k buffer; reused as attention o
  float* V   = f + 4 * SZ;      // v buffer
  float* T   = f + 5 * SZ;      // proj out / ffn accumulate; also kv partials
  float* kv   = f + 6 * SZ;          // 32*4096
  float* ksum = kv + 32 * 4096;      // 32*64
  float* ksp  = ksum + 32 * 64;      // 32*8*64
  int*   flag = (int*)(ksp + 32 * 8 * 64);
  float* kvp  = T;   // kv partials live in T (free at that point)
  float* Fc   = Q;   // FFN hidden chunk lives in Q (free at that point)

  const long W4 = (long)DM * DM;       // 262144

  auto gemm = [&](const float* A, const void* W, long woff, int ldw,
                  const void* bias, long boff, int hasb,
                  float* C, int act, int accum) {
    gemm_k<<<dim3(8, 256), dim3(256), 0, stream>>>(
        A, W, woff, ldw, bias, boff, hasb, C, act, accum, flag);
  };
  auto addln = [&](const float* X, const float* Y, const void* lnp, long lnoff,
                   float* Out) {
    add_ln_k<<<dim3(MROWS), dim3(256), 0, stream>>>(X, Y, lnp, lnoff, Out, flag);
  };
  auto attn = [&](const float* xq, const float* xkv, const void* Wb, long w0,
                  const void* bb, long b0) {
    gemm(xq,  Wb, w0 + 0 * W4, DM, bb, b0 + 0 * DM, 1, Q,  1, 0);
    gemm(xkv, Wb, w0 + 1 * W4, DM, bb, b0 + 1 * DM, 1, Kb, 1, 0);
    gemm(xkv, Wb, w0 + 2 * W4, DM, bb, b0 + 2 * DM, 1, V,  0, 0);
    kv_partial_k<<<dim3(32, 8), dim3(256), 0, stream>>>(Kb, V, kvp, ksp);
    kv_reduce_k<<<dim3(32), dim3(256), 0, stream>>>(kvp, ksp, kv, ksum);
    attn_o_k<<<dim3(32, 64), dim3(256), 0, stream>>>(Q, kv, ksum, Kb);
    gemm(Kb, Wb, w0 + 3 * W4, DM, bb, b0 + 3 * DM, 1, T, 0, 0);
  };
  auto ffn = [&](const float* Hb, const void* W1, long w1b, const void* b1,
                 long b1b, const void* W2, long w2b, const void* b2, long b2b) {
    for (int c = 0; c < 4; c++) {
      gemm(Hb, W1, w1b + c * 512, DFF, b1, b1b + c * 512, 1, Fc, 2, 0);
      gemm(Fc, W2, w2b + (long)c * 512 * DM, DM, b2, b2b, (c == 0) ? 1 : 0, T,
           0, (c == 0) ? 0 : 1);
    }
  };

  detect_k<<<dim3(1), dim3(64), 0, stream>>>((const unsigned*)enc_ln, flag);

  // ---------------- encoder ----------------
  embed_k<<<dim3(32768), dim3(256), 0, stream>>>(x, pe_s, H, flag);
  for (int l = 0; l < 4; l++) {
    attn(H, H, enc_W, (long)l * 4 * W4, enc_b, (long)l * 4 * DM);
    addln(H, T, enc_ln, ((long)l * 2 + 0) * 2 * DM, H);
    ffn(H, enc_fW1, (long)l * DM * DFF, enc_fb1, (long)l * DFF,
        enc_fW2, (long)l * DFF * DM, enc_fb2, (long)l * DM);
    addln(H, T, enc_ln, ((long)l * 2 + 1) * 2 * DM, H);
  }
  addln(H, nullptr, enc_fln, 0, MEM);

  // ---------------- decoder ----------------
  embed_k<<<dim3(32768), dim3(256), 0, stream>>>(tfc, pe_t, H, flag);
  for (int l = 0; l < 4; l++) {
    attn(H, H, dec_W, (long)l * 8 * W4, dec_b, (long)l * 8 * DM);       // self
    addln(H, T, dec_ln, ((long)l * 3 + 0) * 2 * DM, H);
    attn(H, MEM, dec_W, ((long)l * 8 + 4) * W4, dec_b,
         ((long)l * 8 + 4) * DM);                                       // cross
    addln(H, T, dec_ln, ((long)l * 3 + 1) * 2 * DM, H);
    ffn(H, dec_fW1, (long)l * DM * DFF, dec_fb1, (long)l * DFF,
        dec_fW2, (long)l * DFF * DM, dec_fb2, (long)l * DM);
    addln(H, T, dec_ln, ((long)l * 3 + 2) * 2 * DM, H);
  }
  addln(H, nullptr, dec_fln, 0, H);

  heads_k<<<dim3(MROWS / 4), dim3(256), 0, stream>>>(
      H, amp_W, ph_W, amp_b, ph_b, d_out, flag);
}